// Round 4
// baseline (1046.814 us; speedup 1.0000x reference)
//
#include <hip/hip_runtime.h>
#include <math.h>

namespace {
constexpr int kB = 8, kNG = 5, kNL = 75, kNF = 196, kC = 640;
constexpr int kNTokL = kNL * kNF;      // 14700
constexpr int kNTot = kNG + kNTokL;    // 14705
constexpr float kEps = 1e-12f;
constexpr float kInvAlpha = 10.0f;
constexpr int kKC = 20;                // 640 / 32 K-chunks
constexpr int kTiles = 230;            // 64-token tiles per batch
constexpr int kNT = 5;                 // 16-d tiles per wave (wave = 64 tok x 80 d)
}

typedef __attribute__((ext_vector_type(8))) short short8;
typedef __attribute__((ext_vector_type(4))) float floatx4;

union S8U { short8 v; ushort u[8]; };

// round-to-nearest-even bf16 split: x ~= hi + lo
__device__ __forceinline__ void bsplit(float x, ushort& h, ushort& l) {
  union { float f; uint u; } a; a.f = x;
  uint uh = (a.u + 0x7FFFu + ((a.u >> 16) & 1u)) >> 16;
  h = (ushort)uh;
  union { uint u; float f; } bb; bb.u = uh << 16;
  float r = x - bb.f;
  union { float f; uint u; } c; c.f = r;
  l = (ushort)((c.u + 0x7FFFu + ((c.u >> 16) & 1u)) >> 16);
}

#define MFMA_BF16(a, b, c) __builtin_amdgcn_mfma_f32_16x16x32_bf16(a, b, c, 0, 0, 0)

// barrier that does NOT drain vmcnt (keeps global prefetches in flight)
__device__ __forceinline__ void bar_lds() {
  asm volatile("s_waitcnt lgkmcnt(0)\n\ts_barrier" ::: "memory");
}

// async global->LDS: 16 B per lane, LDS dst = wave-uniform base + lane*16,
// global src = per-lane address.
__device__ __forceinline__ void gld_lds16(const float* g, float* l) {
  __builtin_amdgcn_global_load_lds(
      (const __attribute__((address_space(1))) void*)g,
      (__attribute__((address_space(3))) void*)l, 16, 0, 0);
}

// ---------- small kernels ----------

// s_l[b,c] = sum_t local_f[b,t,c]. grid (8,64), block 320 (float4 per lane).
// LDS pair-reduction halves global atomics (640/block, 64 per address total).
__global__ void k_sum_local(const float* __restrict__ lf, float* __restrict__ s_l) {
  const int b = blockIdx.x, slice = blockIdx.y;
  const int tid = threadIdx.x;
  const int c4 = tid % 160, h = tid / 160;       // column group, row half
  const int t0 = slice * 230 + h * 115;
  const int nrow = min(115, kNTokL - t0);
  const float* p = lf + ((size_t)b * kNTokL + t0) * kC + c4 * 4;
  float4 acc = {0.f, 0.f, 0.f, 0.f};
#pragma unroll 2
  for (int i = 0; i < nrow; ++i) {
    const float4 v = *(const float4*)(p + (size_t)i * kC);
    acc.x += v.x; acc.y += v.y; acc.z += v.z; acc.w += v.w;
  }
  __shared__ float4 sred[160];
  if (h == 1) sred[c4] = acc;
  __syncthreads();
  if (h == 0) {
    const float4 o = sred[c4];
    acc.x += o.x; acc.y += o.y; acc.z += o.z; acc.w += o.w;
    float* dst = &s_l[b * kC + c4 * 4];
    atomicAdd(dst + 0, acc.x);
    atomicAdd(dst + 1, acc.y);
    atomicAdd(dst + 2, acc.z);
    atomicAdd(dst + 3, acc.w);
  }
}

// Wk -> Wh/Wl in lane-major MFMA frag tiles, kc-major layout: tile (kc,dt) =
// 512 shorts at (kc*40+dt)*512; lane l (l = quad*16 + n) holds
// W[d = dt*16+n][k = kc*32 + quad*8 .. +8].
__global__ void k_cvtW(const float* __restrict__ Wk, ushort* __restrict__ Wh,
                       ushort* __restrict__ Wl) {
  const int wv = blockIdx.x * 4 + (threadIdx.x >> 6);  // 0..799 = 40 dt x 20 kc
  const int lane = threadIdx.x & 63;
  const int kc = wv % kKC, dt = wv / kKC;
  const int fm = lane & 15, quad = lane >> 4;
  const float* p = Wk + (size_t)(dt * 16 + fm) * kC + kc * 32 + quad * 8;
  float4 a = *(const float4*)p;
  float4 c = *(const float4*)(p + 4);
  S8U h, l;
  bsplit(a.x, h.u[0], l.u[0]); bsplit(a.y, h.u[1], l.u[1]);
  bsplit(a.z, h.u[2], l.u[2]); bsplit(a.w, h.u[3], l.u[3]);
  bsplit(c.x, h.u[4], l.u[4]); bsplit(c.y, h.u[5], l.u[5]);
  bsplit(c.z, h.u[6], l.u[6]); bsplit(c.w, h.u[7], l.u[7]);
  const size_t off = ((size_t)kc * 40 + dt) * 512 + (size_t)lane * 8;
  *(short8*)(Wh + off) = h.v;
  *(short8*)(Wl + off) = l.v;
}

// One wave per (b,d): m[b,d] = (Wq[d]·sum_g gf + Wk[d]·s_l[b]) / 14705
// gc[b,g,d] = Wq[d]·gf[b,g] - m[b,d]
__global__ void k_proj_mean(const float* __restrict__ Wq, const float* __restrict__ Wk,
                            const float* __restrict__ gf, const float* __restrict__ s_l,
                            float* __restrict__ m, float* __restrict__ gc) {
  const int wid = blockIdx.x * 4 + (threadIdx.x >> 6);
  const int lane = threadIdx.x & 63;
  const int b = wid / kC, d = wid % kC;
  float ak = 0.f, ag[kNG] = {0.f, 0.f, 0.f, 0.f, 0.f};
  for (int c = lane; c < kC; c += 64) {
    const float wq = Wq[d * kC + c];
    const float wk = Wk[d * kC + c];
    ak += wk * s_l[b * kC + c];
#pragma unroll
    for (int g = 0; g < kNG; ++g) ag[g] += wq * gf[(b * kNG + g) * kC + c];
  }
#pragma unroll
  for (int off = 32; off > 0; off >>= 1) {
    ak += __shfl_xor(ak, off);
#pragma unroll
    for (int g = 0; g < kNG; ++g) ag[g] += __shfl_xor(ag[g], off);
  }
  if (lane == 0) {
    float aq = 0.f;
#pragma unroll
    for (int g = 0; g < kNG; ++g) aq += ag[g];
    const float mv = (aq + ak) / (float)kNTot;
    m[b * kC + d] = mv;
#pragma unroll
    for (int g = 0; g < kNG; ++g) gc[(b * kNG + g) * kC + d] = ag[g] - mv;
  }
}

__global__ void k_norm_g(const float* __restrict__ gc, float* __restrict__ gn) {
  const int row = blockIdx.x;
  __shared__ float red[256];
  float a = 0.f;
  for (int d = threadIdx.x; d < kC; d += 256) {
    const float v = gc[row * kC + d];
    a += v * v;
  }
  red[threadIdx.x] = a;
  __syncthreads();
  for (int s = 128; s > 0; s >>= 1) {
    if (threadIdx.x < s) red[threadIdx.x] += red[threadIdx.x + s];
    __syncthreads();
  }
  const float rs = 1.0f / sqrtf(red[0] + kEps);
  for (int d = threadIdx.x; d < kC; d += 256) gn[row * kC + d] = gc[row * kC + d] * rs;
}

// ---------- the big fused kernel ----------
// Block = 64 tokens x ALL 640 d. 8 waves, wave wn = 64 tok x 80 d (5 nt tiles).
// A path: raw fp32 lf DMA'd to LDS via global_load_lds with per-lane
// frag-gather source addresses (no staging VALU / ds_writes); hi/lo bf16
// split happens after ds_read, in the MFMA shadow. K-step = 128 (4 sub-chunks
// per barrier, 5 barriers total), LDS 2 x 32 KB double-buffered, prefetch
// distance = 1 full iteration (~9000 cy >> HBM latency) so the vmcnt(0)
// drain at the barrier is free. B fragments: per-nt JIT double-buffered
// loads from L2 (bounded 16 VGPRs). Per-accumulator MFMA order unchanged
// -> bit-identical output.
__global__ __launch_bounds__(512, 1) void k_big(
    const float* __restrict__ lf, const ushort* __restrict__ Wh,
    const ushort* __restrict__ Wl, const float* __restrict__ m,
    const float* __restrict__ gn, float* __restrict__ scores) {
  __shared__ float smem[16384];  // 64 KB: buf0 @ 0, buf1 @ 8192 floats
  float* red = smem;             // epilogue overlay [8 waves][64 rows][6]

  const int tid = threadIdx.x;
  const int wn = tid >> 6, lane = tid & 63;
  const int fm = lane & 15, quad = lane >> 4;
  const int b = blockIdx.x & 7, tile = blockIdx.x >> 3;
  const int tok0 = tile * 64;

  // A-staging: per 128-k iteration the block needs 16 fp32 tiles
  // (sub s=0..3, mt=0..3), tile ti = s*4+mt = 16 tok x 32 k = 512 floats.
  // Wave wn DMAs tiles {2wn, 2wn+1}, 2 x gld_lds16 each (j2 halves).
  // Within a tile: float offset = j2*256 + lane*4, where lane = quad*16+fm
  // holds tok = mt*16+fm, k = quad*8 + j2*4 .. +4.   (matches MFMA A-frag)
  const int ti0 = wn * 2;
  int r0 = tok0 + (ti0 & 3) * 16 + fm;
  int r1 = tok0 + ((ti0 + 1) & 3) * 16 + fm;
  if (r0 >= kNTokL) r0 = kNTokL - 1;  // clamp: pad rows read row 14699 (unused)
  if (r1 >= kNTokL) r1 = kNTokL - 1;
  const float* sg0 = lf + ((size_t)b * kNTokL + r0) * kC + (ti0 >> 2) * 32 + quad * 8;
  const float* sg1 = lf + ((size_t)b * kNTokL + r1) * kC + ((ti0 + 1) >> 2) * 32 + quad * 8;

  floatx4 acc[4][kNT];
#pragma unroll
  for (int i = 0; i < 4; ++i)
#pragma unroll
    for (int j = 0; j < kNT; ++j) acc[i][j] = (floatx4){0.f, 0.f, 0.f, 0.f};

#define ISSUE_A(BUFF, KC128)                                        \
  {                                                                 \
    const float* _s0 = sg0 + (KC128) * 128;                         \
    const float* _s1 = sg1 + (KC128) * 128;                         \
    float* _d = smem + (BUFF) + ti0 * 512;                          \
    gld_lds16(_s0, _d);                                             \
    gld_lds16(_s0 + 4, _d + 256);                                   \
    gld_lds16(_s1, _d + 512);                                       \
    gld_lds16(_s1 + 4, _d + 768);                                   \
  }

  // read+convert the 4 mt fragments of sub-chunk s from LDS
#define READCVT(BUFF, S)                                                      \
  {                                                                           \
    _Pragma("unroll") for (int mt = 0; mt < 4; ++mt) {                        \
      const float* _t = smem + (BUFF) + ((S) * 4 + mt) * 512;                 \
      floatx4 f0 = *(const floatx4*)(_t + lane * 4);                          \
      floatx4 f1 = *(const floatx4*)(_t + 256 + lane * 4);                    \
      S8U _h, _l;                                                             \
      bsplit(f0[0], _h.u[0], _l.u[0]); bsplit(f0[1], _h.u[1], _l.u[1]);       \
      bsplit(f0[2], _h.u[2], _l.u[2]); bsplit(f0[3], _h.u[3], _l.u[3]);       \
      bsplit(f1[0], _h.u[4], _l.u[4]); bsplit(f1[1], _h.u[5], _l.u[5]);       \
      bsplit(f1[2], _h.u[6], _l.u[6]); bsplit(f1[3], _h.u[7], _l.u[7]);       \
      ah[mt] = _h.v; al[mt] = _l.v;                                           \
    }                                                                         \
  }

  // one 32-k sub-chunk: convert A, then per-nt JIT B (double-buffered) + 12
  // MFMAs. Per-acc order hh -> lh -> hl, identical to previous versions.
#define DOSUB(BUFF, S, KCI)                                                   \
  {                                                                           \
    READCVT(BUFF, S);                                                         \
    const ushort* _bh = Wh + ((size_t)(KCI) * 40 + wn * 5) * 512 + (size_t)lane * 8; \
    const ushort* _bl = Wl + ((size_t)(KCI) * 40 + wn * 5) * 512 + (size_t)lane * 8; \
    short8 bhc = *(const short8*)_bh;                                         \
    short8 blc = *(const short8*)_bl;                                         \
    _Pragma("unroll") for (int nt = 0; nt < kNT; ++nt) {                      \
      short8 bhn = bhc, bln = blc;                                            \
      if (nt + 1 < kNT) {                                                     \
        bhn = *(const short8*)(_bh + (nt + 1) * 512);                         \
        bln = *(const short8*)(_bl + (nt + 1) * 512);                         \
      }                                                                       \
      _Pragma("unroll") for (int mt = 0; mt < 4; ++mt)                        \
          acc[mt][nt] = MFMA_BF16(ah[mt], bhc, acc[mt][nt]);                  \
      _Pragma("unroll") for (int mt = 0; mt < 4; ++mt)                        \
          acc[mt][nt] = MFMA_BF16(al[mt], bhc, acc[mt][nt]);                  \
      _Pragma("unroll") for (int mt = 0; mt < 4; ++mt)                        \
          acc[mt][nt] = MFMA_BF16(ah[mt], blc, acc[mt][nt]);                  \
      bhc = bhn; blc = bln;                                                   \
    }                                                                         \
  }

  short8 ah[4], al[4];
  ISSUE_A(0, 0);  // prologue: iteration-0 A into buf0
  for (int t = 0; t < 5; ++t) {
    const int buff = (t & 1) * 8192;
    // own DMA (issued a full iteration ago) + own LDS reads of the other
    // buffer are drained, then sync: after barrier all waves' A is in LDS.
    asm volatile("s_waitcnt vmcnt(0) lgkmcnt(0)\n\ts_barrier" ::: "memory");
    if (t < 4) ISSUE_A(((t & 1) ^ 1) * 8192, t + 1);  // next iter, in flight across MFMA
    DOSUB(buff, 0, t * 4 + 0);
    DOSUB(buff, 1, t * 4 + 1);
    DOSUB(buff, 2, t * 4 + 2);
    DOSUB(buff, 3, t * 4 + 3);
  }

  // ---- epilogue: center, reduce over d, combine 8 waves, write scores ----
  float mv[kNT], gvv[5][kNT];
#pragma unroll
  for (int nt = 0; nt < kNT; ++nt) {
    const int d = wn * 80 + nt * 16 + fm;
    mv[nt] = m[b * kC + d];
#pragma unroll
    for (int g = 0; g < 5; ++g) gvv[g][nt] = gn[(b * kNG + g) * kC + d];
  }

  bar_lds();  // all waves' K-loop ds_reads done before red[] overwrites buf0
#pragma unroll
  for (int mt = 0; mt < 4; ++mt)
#pragma unroll
    for (int reg = 0; reg < 4; ++reg) {
      float part[6] = {0.f, 0.f, 0.f, 0.f, 0.f, 0.f};
#pragma unroll
      for (int nt = 0; nt < kNT; ++nt) {
        const float yc = acc[mt][nt][reg] - mv[nt];
        part[0] += yc * yc;
#pragma unroll
        for (int g = 0; g < 5; ++g) part[1 + g] += yc * gvv[g][nt];
      }
#pragma unroll
      for (int off = 1; off < 16; off <<= 1)
#pragma unroll
        for (int v = 0; v < 6; ++v) part[v] += __shfl_xor(part[v], off);
      if (fm == 0) {
        const int row = mt * 16 + quad * 4 + reg;
#pragma unroll
        for (int v = 0; v < 6; ++v) red[((size_t)wn * 64 + row) * 6 + v] = part[v];
      }
    }
  bar_lds();
  if (tid < 64) {
    const int tok = tok0 + tid;
    if (tok < kNTokL) {
      float s[6] = {0.f, 0.f, 0.f, 0.f, 0.f, 0.f};
#pragma unroll
      for (int w = 0; w < 8; ++w)
#pragma unroll
        for (int v = 0; v < 6; ++v) s[v] += red[((size_t)w * 64 + tid) * 6 + v];
      const float rs = (1.0f / sqrtf(s[0] + kEps)) * kInvAlpha;
      const size_t t = (size_t)b * kNTokL + tok;
#pragma unroll
      for (int g = 0; g < 5; ++g)
        scores[(size_t)g * (kB * kNTokL) + t] = s[1 + g] * rs;
    }
  }
#undef ISSUE_A
#undef READCVT
#undef DOSUB
}

// softmax over f (196) per (b,l,g) row; one wave per row. scores pre-scaled.
__global__ void k_softmax(const float* __restrict__ scores, float* __restrict__ out) {
  const int wid = blockIdx.x * 4 + (threadIdx.x >> 6);
  const int lane = threadIdx.x & 63;
  const int b = wid / (kNL * kNG);
  const int rem = wid % (kNL * kNG);
  const int l = rem / kNG, g = rem % kNG;
  float sv[4];
  float mx = -1e30f;
#pragma unroll
  for (int u = 0; u < 4; ++u) {
    const int f = lane + 64 * u;
    if (f < kNF) {
      const size_t t = (size_t)b * kNTokL + (size_t)l * kNF + f;
      sv[u] = scores[(size_t)g * (kB * kNTokL) + t];
      mx = fmaxf(mx, sv[u]);
    } else {
      sv[u] = 0.f;
    }
  }
#pragma unroll
  for (int off = 32; off > 0; off >>= 1) mx = fmaxf(mx, __shfl_xor(mx, off));
  float se = 0.f;
#pragma unroll
  for (int u = 0; u < 4; ++u) {
    const int f = lane + 64 * u;
    const float e = (f < kNF) ? expf(sv[u] - mx) : 0.f;
    sv[u] = e;
    se += e;
  }
#pragma unroll
  for (int off = 32; off > 0; off >>= 1) se += __shfl_xor(se, off);
  const float inv = 1.0f / se;
#pragma unroll
  for (int u = 0; u < 4; ++u) {
    const int f = lane + 64 * u;
    if (f < kNF) out[((size_t)(b * kNL + l) * kNG + g) * kNF + f] = sv[u] * inv;
  }
}

// ===================== launcher =====================

extern "C" void kernel_launch(void* const* d_in, const int* in_sizes, int n_in,
                              void* d_out, int out_size, void* d_ws, size_t ws_size,
                              hipStream_t stream) {
  (void)in_sizes; (void)n_in; (void)out_size; (void)ws_size;
  const float* gf = (const float*)d_in[0];  // [8,5,640]
  const float* lf = (const float*)d_in[1];  // [8,75,196,640]
  const float* Wq = (const float*)d_in[2];  // [640,640]
  const float* Wk = (const float*)d_in[3];  // [640,640]
  float* ws = (float*)d_ws;
  float* out = (float*)d_out;

  // workspace (float offsets): total ~4.2 MB
  float* s_l    = ws;            // 5120
  float* m      = ws + 5120;     // 5120
  float* gc     = ws + 10240;    // 25600
  float* gn     = ws + 35840;    // 25600
  float* scores = ws + 61440;    // 5*117600 = 588000  (layout [g][t])
  ushort* Wh    = (ushort*)(ws + 649440);  // 409600 shorts
  ushort* Wl    = (ushort*)(ws + 854240);  // 409600 shorts

  hipMemsetAsync(s_l, 0, (size_t)5120 * 4, stream);

  k_sum_local<<<dim3(kB, 64), 320, 0, stream>>>(lf, s_l);
  k_cvtW<<<200, 256, 0, stream>>>(Wk, Wh, Wl);
  k_proj_mean<<<(kB * kC) / 4, 256, 0, stream>>>(Wq, Wk, gf, s_l, m, gc);
  k_norm_g<<<kB * kNG, 256, 0, stream>>>(gc, gn);
  k_big<<<kTiles * kB, 512, 0, stream>>>(lf, Wh, Wl, m, gn, scores);
  k_softmax<<<750, 256, 0, stream>>>(scores, out);
}

// Round 5
// 834.315 us; speedup vs baseline: 1.2547x; 1.2547x over previous
//
#include <hip/hip_runtime.h>
#include <math.h>

namespace {
constexpr int kB = 8, kNG = 5, kNL = 75, kNF = 196, kC = 640;
constexpr int kNTokL = kNL * kNF;      // 14700
constexpr int kNTot = kNG + kNTokL;    // 14705
constexpr float kEps = 1e-12f;
constexpr float kInvAlpha = 10.0f;
constexpr int kKC = 20;                // 640 / 32 K-chunks
constexpr int kTiles = 230;            // 64-token tiles per batch
constexpr int kNT = 5;                 // 16-d tiles per wave (wave = 32 tok x 80 d)
}

typedef __attribute__((ext_vector_type(8))) short short8;
typedef __attribute__((ext_vector_type(4))) short short4v;
typedef __attribute__((ext_vector_type(4))) float floatx4;

union S8U { short8 v; ushort u[8]; };
union S4U { short4v v; ushort u[4]; };

// round-to-nearest-even bf16 split: x ~= hi + lo
__device__ __forceinline__ void bsplit(float x, ushort& h, ushort& l) {
  union { float f; uint u; } a; a.f = x;
  uint uh = (a.u + 0x7FFFu + ((a.u >> 16) & 1u)) >> 16;
  h = (ushort)uh;
  union { uint u; float f; } bb; bb.u = uh << 16;
  float r = x - bb.f;
  union { float f; uint u; } c; c.f = r;
  l = (ushort)((c.u + 0x7FFFu + ((c.u >> 16) & 1u)) >> 16);
}

#define MFMA_BF16(a, b, c) __builtin_amdgcn_mfma_f32_16x16x32_bf16(a, b, c, 0, 0, 0)

// barrier that does NOT drain vmcnt (keeps global prefetches in flight)
__device__ __forceinline__ void bar_lds() {
  asm volatile("s_waitcnt lgkmcnt(0)\n\ts_barrier" ::: "memory");
}

// ---------- fused small kernel: lf column-sum + Wk bf16-split conversion ----------
// blocks 0..1839: s_l[b,c] += sum of a 64-row slice (LDS pair-reduce, then atomics)
// blocks 1840..1999: Wk -> Wh/Wl frag tiles, kc-major: tile (kc,dt) = 512 shorts
//   at (kc*40+dt)*512; lane (quad*16+n) holds W[d=dt*16+n][k=kc*32+quad*8..+8].
__global__ void k_sumcvt(const float* __restrict__ lf, float* __restrict__ s_l,
                         const float* __restrict__ Wk, ushort* __restrict__ Wh,
                         ushort* __restrict__ Wl) {
  const int tid = threadIdx.x;
  if (blockIdx.x < 1840) {
    const int b = blockIdx.x & 7, slice = blockIdx.x >> 3;
    const int c4 = tid % 160, h = tid / 160;     // column group, row half
    const int t0 = slice * 64 + h * 32;
    const int nrow = min(32, kNTokL - t0);
    const float* p = lf + ((size_t)b * kNTokL + t0) * kC + c4 * 4;
    float4 acc = {0.f, 0.f, 0.f, 0.f};
#pragma unroll 4
    for (int i = 0; i < nrow; ++i) {
      const float4 v = *(const float4*)(p + (size_t)i * kC);
      acc.x += v.x; acc.y += v.y; acc.z += v.z; acc.w += v.w;
    }
    __shared__ float4 sred[160];
    if (h == 1) sred[c4] = acc;
    __syncthreads();
    if (h == 0) {
      const float4 o = sred[c4];
      acc.x += o.x; acc.y += o.y; acc.z += o.z; acc.w += o.w;
      float* dst = &s_l[b * kC + c4 * 4];
      atomicAdd(dst + 0, acc.x);
      atomicAdd(dst + 1, acc.y);
      atomicAdd(dst + 2, acc.z);
      atomicAdd(dst + 3, acc.w);
    }
  } else {
    const int wv = (blockIdx.x - 1840) * 5 + (tid >> 6);  // 0..799 = 40 dt x 20 kc
    const int lane = tid & 63;
    const int kc = wv % kKC, dt = wv / kKC;
    const int fm = lane & 15, quad = lane >> 4;
    const float* p = Wk + (size_t)(dt * 16 + fm) * kC + kc * 32 + quad * 8;
    float4 a = *(const float4*)p;
    float4 c = *(const float4*)(p + 4);
    S8U h, l;
    bsplit(a.x, h.u[0], l.u[0]); bsplit(a.y, h.u[1], l.u[1]);
    bsplit(a.z, h.u[2], l.u[2]); bsplit(a.w, h.u[3], l.u[3]);
    bsplit(c.x, h.u[4], l.u[4]); bsplit(c.y, h.u[5], l.u[5]);
    bsplit(c.z, h.u[6], l.u[6]); bsplit(c.w, h.u[7], l.u[7]);
    const size_t off = ((size_t)kc * 40 + dt) * 512 + (size_t)lane * 8;
    *(short8*)(Wh + off) = h.v;
    *(short8*)(Wl + off) = l.v;
  }
}

// One wave per (b,d): m[b,d] = (Wq[d]·sum_g gf + Wk[d]·s_l[b]) / 14705
// gc[b,g,d] = Wq[d]·gf[b,g] - m[b,d]
__global__ void k_proj_mean(const float* __restrict__ Wq, const float* __restrict__ Wk,
                            const float* __restrict__ gf, const float* __restrict__ s_l,
                            float* __restrict__ m, float* __restrict__ gc) {
  const int wid = blockIdx.x * 4 + (threadIdx.x >> 6);
  const int lane = threadIdx.x & 63;
  const int b = wid / kC, d = wid % kC;
  float ak = 0.f, ag[kNG] = {0.f, 0.f, 0.f, 0.f, 0.f};
  for (int c = lane; c < kC; c += 64) {
    const float wq = Wq[d * kC + c];
    const float wk = Wk[d * kC + c];
    ak += wk * s_l[b * kC + c];
#pragma unroll
    for (int g = 0; g < kNG; ++g) ag[g] += wq * gf[(b * kNG + g) * kC + c];
  }
#pragma unroll
  for (int off = 32; off > 0; off >>= 1) {
    ak += __shfl_xor(ak, off);
#pragma unroll
    for (int g = 0; g < kNG; ++g) ag[g] += __shfl_xor(ag[g], off);
  }
  if (lane == 0) {
    float aq = 0.f;
#pragma unroll
    for (int g = 0; g < kNG; ++g) aq += ag[g];
    const float mv = (aq + ak) / (float)kNTot;
    m[b * kC + d] = mv;
#pragma unroll
    for (int g = 0; g < kNG; ++g) gc[(b * kNG + g) * kC + d] = ag[g] - mv;
  }
}

__global__ void k_norm_g(const float* __restrict__ gc, float* __restrict__ gn) {
  const int row = blockIdx.x;
  __shared__ float red[256];
  float a = 0.f;
  for (int d = threadIdx.x; d < kC; d += 256) {
    const float v = gc[row * kC + d];
    a += v * v;
  }
  red[threadIdx.x] = a;
  __syncthreads();
  for (int s = 128; s > 0; s >>= 1) {
    if (threadIdx.x < s) red[threadIdx.x] += red[threadIdx.x + s];
    __syncthreads();
  }
  const float rs = 1.0f / sqrtf(red[0] + kEps);
  for (int d = threadIdx.x; d < kC; d += 256) gn[row * kC + d] = gc[row * kC + d] * rs;
}

// ---------- the big fused kernel ----------
// Block = 64 tokens x ALL 640 d. 1024 threads = 16 waves; wave (wn,th) =
// 32 tok (half th) x 80 d (slice wn). acc = 40 f32/lane -> total regs ~120
// => 4 waves/SIMD (2x round-1 occupancy): latency of B JIT loads + ds_reads
// hides across waves. A staged ONCE per block as bf16 hi/lo via ds_write
// (conversion off the per-wave path). K-step 64 (10 barriers). Per-acc
// MFMA chain (kc asc; hh->lh->hl) identical to round-1 -> bit-identical.
__global__ __launch_bounds__(1024, 4) void k_big(
    const float* __restrict__ lf, const ushort* __restrict__ Wh,
    const ushort* __restrict__ Wl, const float* __restrict__ m,
    const float* __restrict__ gn, float* __restrict__ scores) {
  __shared__ ushort smem[16384];  // 32 KB: buf t&1 @ (t&1)*8192; H @ +0, L @ +4096
  float* red = (float*)smem;      // epilogue overlay [16 waves][32 rows][6]

  const int tid = threadIdx.x;
  const int wv = tid >> 6, lane = tid & 63;
  const int wn = wv >> 1, th2 = (wv & 1) * 2;   // d-slice, token-half tile base
  const int fm = lane & 15, quad = lane >> 4;
  const int b = blockIdx.x & 7, tile = blockIdx.x >> 3;
  const int tok0 = tile * 64;

  // staging role: token row sr (0..63), float4 k-group sq (0..15) within 64-k step
  const int sr = tid >> 4, sq = tid & 15;
  int strow = tok0 + sr;
  if (strow >= kNTokL) strow = kNTokL - 1;  // clamp: pad rows reuse last row (never written)
  const float* xrow = lf + ((size_t)b * kNTokL + strow) * kC + sq * 4;
  // LDS offset (shorts): subchunk ci = sq>>3, tile (ci*4 + sr>>4),
  // lane' = (kq>>1)*16 + (sr&15), j = kq&1  (matches MFMA A-frag layout)
  const int kq = sq & 7;
  const int aoff = ((sq >> 3) * 4 + (sr >> 4)) * 512 + ((kq >> 1) * 16 + (sr & 15)) * 8 + (kq & 1) * 4;

  floatx4 acc[2][kNT];
#pragma unroll
  for (int i = 0; i < 2; ++i)
#pragma unroll
    for (int j = 0; j < kNT; ++j) acc[i][j] = (floatx4){0.f, 0.f, 0.f, 0.f};

#define STAGE(XV, BUF)                                        \
  {                                                           \
    S4U _h, _l;                                               \
    bsplit((XV).x, _h.u[0], _l.u[0]);                         \
    bsplit((XV).y, _h.u[1], _l.u[1]);                         \
    bsplit((XV).z, _h.u[2], _l.u[2]);                         \
    bsplit((XV).w, _h.u[3], _l.u[3]);                         \
    *(short4v*)(smem + (BUF) + aoff) = _h.v;                  \
    *(short4v*)(smem + (BUF) + 4096 + aoff) = _l.v;           \
  }

#define LOADB(KCI)                                                            \
  {                                                                           \
    const size_t _o = ((size_t)(KCI) * 40 + wn * 5) * 512 + (size_t)lane * 8; \
    _Pragma("unroll") for (int nt = 0; nt < kNT; ++nt) {                      \
      BH[nt] = *(const short8*)(Wh + _o + nt * 512);                          \
      BL[nt] = *(const short8*)(Wl + _o + nt * 512);                          \
    }                                                                         \
  }

#define READA(BUF, CI)                                                        \
  {                                                                           \
    _Pragma("unroll") for (int mt = 0; mt < 2; ++mt) {                        \
      const int _ba = (BUF) + ((CI) * 4 + th2 + mt) * 512 + lane * 8;         \
      ah[mt] = *(const short8*)(smem + _ba);                                  \
      al[mt] = *(const short8*)(smem + _ba + 4096);                           \
    }                                                                         \
  }

  // 3 independent passes of 10 MFMAs; per-acc order hh -> lh -> hl
#define DOMFMA3                                                               \
  {                                                                           \
    _Pragma("unroll") for (int nt = 0; nt < kNT; ++nt)                        \
        _Pragma("unroll") for (int mt = 0; mt < 2; ++mt)                      \
            acc[mt][nt] = MFMA_BF16(ah[mt], BH[nt], acc[mt][nt]);             \
    _Pragma("unroll") for (int nt = 0; nt < kNT; ++nt)                        \
        _Pragma("unroll") for (int mt = 0; mt < 2; ++mt)                      \
            acc[mt][nt] = MFMA_BF16(al[mt], BH[nt], acc[mt][nt]);             \
    _Pragma("unroll") for (int nt = 0; nt < kNT; ++nt)                        \
        _Pragma("unroll") for (int mt = 0; mt < 2; ++mt)                      \
            acc[mt][nt] = MFMA_BF16(ah[mt], BL[nt], acc[mt][nt]);             \
  }

  short8 ah[2], al[2];
  short8 BH[kNT], BL[kNT];
  // prologue: stage K-step 0 into buf0; prefetch K-step 1 globals
  float4 xcur = *(const float4*)xrow;
  STAGE(xcur, 0);
  float4 xnext = *(const float4*)(xrow + 64);
  for (int t = 0; t < 10; ++t) {
    const int buff = (t & 1) * 8192;
    bar_lds();                                  // stage writes for t visible; reads of other buf done
    if (t < 9) STAGE(xnext, ((t + 1) & 1) * 8192);
    if (t < 8) xnext = *(const float4*)(xrow + (t + 2) * 64);
    LOADB(2 * t);                               // B for sub 0 (L2, in flight over ds_reads)
    READA(buff, 0);
    DOMFMA3;
    LOADB(2 * t + 1);                           // B for sub 1
    READA(buff, 1);
    DOMFMA3;
  }

  // ---- epilogue: center, reduce over d, combine 16 waves, write scores ----
  float mv[kNT], gvv[5][kNT];
#pragma unroll
  for (int nt = 0; nt < kNT; ++nt) {
    const int d = wn * 80 + nt * 16 + fm;
    mv[nt] = m[b * kC + d];
#pragma unroll
    for (int g = 0; g < 5; ++g) gvv[g][nt] = gn[(b * kNG + g) * kC + d];
  }

  bar_lds();  // all waves' K-loop ds_reads done before red[] overwrites bufs
#pragma unroll
  for (int mt = 0; mt < 2; ++mt)
#pragma unroll
    for (int reg = 0; reg < 4; ++reg) {
      float part[6] = {0.f, 0.f, 0.f, 0.f, 0.f, 0.f};
#pragma unroll
      for (int nt = 0; nt < kNT; ++nt) {
        const float yc = acc[mt][nt][reg] - mv[nt];
        part[0] += yc * yc;
#pragma unroll
        for (int g = 0; g < 5; ++g) part[1 + g] += yc * gvv[g][nt];
      }
#pragma unroll
      for (int off = 1; off < 16; off <<= 1)
#pragma unroll
        for (int v = 0; v < 6; ++v) part[v] += __shfl_xor(part[v], off);
      if (fm == 0) {
        const int row = mt * 16 + quad * 4 + reg;   // 0..31 within the wave's 32 tokens
#pragma unroll
        for (int v = 0; v < 6; ++v) red[((size_t)wv * 32 + row) * 6 + v] = part[v];
      }
    }
  bar_lds();
  if (tid < 64) {
    const int tok = tok0 + tid;
    if (tok < kNTokL) {
      const int tht = tid >> 5, row = tid & 31;
      float s[6] = {0.f, 0.f, 0.f, 0.f, 0.f, 0.f};
#pragma unroll
      for (int w = 0; w < 8; ++w)   // d-slices ascending (same order as round-1)
#pragma unroll
        for (int v = 0; v < 6; ++v) s[v] += red[((size_t)(w * 2 + tht) * 32 + row) * 6 + v];
      const float rs = (1.0f / sqrtf(s[0] + kEps)) * kInvAlpha;
      const size_t t = (size_t)b * kNTokL + tok;
#pragma unroll
      for (int g = 0; g < 5; ++g)
        scores[(size_t)g * (kB * kNTokL) + t] = s[1 + g] * rs;
    }
  }
#undef STAGE
#undef LOADB
#undef READA
#undef DOMFMA3
}

// softmax over f (196) per (b,l,g) row; one wave per row. scores pre-scaled.
__global__ void k_softmax(const float* __restrict__ scores, float* __restrict__ out) {
  const int wid = blockIdx.x * 4 + (threadIdx.x >> 6);
  const int lane = threadIdx.x & 63;
  const int b = wid / (kNL * kNG);
  const int rem = wid % (kNL * kNG);
  const int l = rem / kNG, g = rem % kNG;
  float sv[4];
  float mx = -1e30f;
#pragma unroll
  for (int u = 0; u < 4; ++u) {
    const int f = lane + 64 * u;
    if (f < kNF) {
      const size_t t = (size_t)b * kNTokL + (size_t)l * kNF + f;
      sv[u] = scores[(size_t)g * (kB * kNTokL) + t];
      mx = fmaxf(mx, sv[u]);
    } else {
      sv[u] = 0.f;
    }
  }
#pragma unroll
  for (int off = 32; off > 0; off >>= 1) mx = fmaxf(mx, __shfl_xor(mx, off));
  float se = 0.f;
#pragma unroll
  for (int u = 0; u < 4; ++u) {
    const int f = lane + 64 * u;
    const float e = (f < kNF) ? expf(sv[u] - mx) : 0.f;
    sv[u] = e;
    se += e;
  }
#pragma unroll
  for (int off = 32; off > 0; off >>= 1) se += __shfl_xor(se, off);
  const float inv = 1.0f / se;
#pragma unroll
  for (int u = 0; u < 4; ++u) {
    const int f = lane + 64 * u;
    if (f < kNF) out[((size_t)(b * kNL + l) * kNG + g) * kNF + f] = sv[u] * inv;
  }
}

// ===================== launcher =====================

extern "C" void kernel_launch(void* const* d_in, const int* in_sizes, int n_in,
                              void* d_out, int out_size, void* d_ws, size_t ws_size,
                              hipStream_t stream) {
  (void)in_sizes; (void)n_in; (void)out_size; (void)ws_size;
  const float* gf = (const float*)d_in[0];  // [8,5,640]
  const float* lf = (const float*)d_in[1];  // [8,75,196,640]
  const float* Wq = (const float*)d_in[2];  // [640,640]
  const float* Wk = (const float*)d_in[3];  // [640,640]
  float* ws = (float*)d_ws;
  float* out = (float*)d_out;

  // workspace (float offsets): total ~4.2 MB
  float* s_l    = ws;            // 5120
  float* m      = ws + 5120;     // 5120
  float* gc     = ws + 10240;    // 25600
  float* gn     = ws + 35840;    // 25600
  float* scores = ws + 61440;    // 5*117600 = 588000  (layout [g][t])
  ushort* Wh    = (ushort*)(ws + 649440);  // 409600 shorts
  ushort* Wl    = (ushort*)(ws + 854240);  // 409600 shorts

  hipMemsetAsync(s_l, 0, (size_t)5120 * 4, stream);

  k_sumcvt<<<2000, 320, 0, stream>>>(lf, s_l, Wk, Wh, Wl);
  k_proj_mean<<<(kB * kC) / 4, 256, 0, stream>>>(Wq, Wk, gf, s_l, m, gc);
  k_norm_g<<<kB * kNG, 256, 0, stream>>>(gc, gn);
  k_big<<<kTiles * kB, 1024, 0, stream>>>(lf, Wh, Wl, m, gn, scores);
  k_softmax<<<750, 256, 0, stream>>>(scores, out);
}

// Round 8
// 746.562 us; speedup vs baseline: 1.4022x; 1.1175x over previous
//
#include <hip/hip_runtime.h>
#include <math.h>

namespace {
constexpr int kB = 8, kNG = 5, kNL = 75, kNF = 196, kC = 640;
constexpr int kNTokL = kNL * kNF;      // 14700
constexpr int kNTot = kNG + kNTokL;    // 14705
constexpr float kEps = 1e-12f;
constexpr float kInvAlpha = 10.0f;
constexpr int kKC = 20;                // 640 / 32 K-chunks
constexpr int kTiles = 115;            // 128-token tiles per batch
constexpr int kNT = 5;                 // 16-d tiles per wave (wave = 128 tok x 80 d)
}

typedef __attribute__((ext_vector_type(8))) short short8;
typedef __attribute__((ext_vector_type(4))) float floatx4;

union S8U { short8 v; ushort u[8]; };

// round-to-nearest-even bf16 split: x ~= hi + lo
__device__ __forceinline__ void bsplit(float x, ushort& h, ushort& l) {
  union { float f; uint u; } a; a.f = x;
  uint uh = (a.u + 0x7FFFu + ((a.u >> 16) & 1u)) >> 16;
  h = (ushort)uh;
  union { uint u; float f; } bb; bb.u = uh << 16;
  float r = x - bb.f;
  union { float f; uint u; } c; c.f = r;
  l = (ushort)((c.u + 0x7FFFu + ((c.u >> 16) & 1u)) >> 16);
}

#define MFMA_BF16(a, b, c) __builtin_amdgcn_mfma_f32_16x16x32_bf16(a, b, c, 0, 0, 0)

// barrier that does NOT drain vmcnt (keeps global prefetches in flight)
__device__ __forceinline__ void bar_lds() {
  asm volatile("s_waitcnt lgkmcnt(0)\n\ts_barrier" ::: "memory");
}

// ---------- fused small kernel: lf column-sum + Wk bf16-split conversion ----------
// blocks 0..1839: s_l[b,c] += sum of a 64-row slice (LDS pair-reduce, then atomics)
// blocks 1840..1999: Wk -> Wh/Wl frag tiles, kc-major: tile (kc,dt) = 512 shorts
//   at (kc*40+dt)*512; lane (quad*16+n) holds W[d=dt*16+n][k=kc*32+quad*8..+8].
__global__ void k_sumcvt(const float* __restrict__ lf, float* __restrict__ s_l,
                         const float* __restrict__ Wk, ushort* __restrict__ Wh,
                         ushort* __restrict__ Wl) {
  const int tid = threadIdx.x;
  if (blockIdx.x < 1840) {
    const int b = blockIdx.x & 7, slice = blockIdx.x >> 3;
    const int c4 = tid % 160, h = tid / 160;     // column group, row half
    const int t0 = slice * 64 + h * 32;
    const int nrow = min(32, kNTokL - t0);
    const float* p = lf + ((size_t)b * kNTokL + t0) * kC + c4 * 4;
    float4 acc = {0.f, 0.f, 0.f, 0.f};
#pragma unroll 4
    for (int i = 0; i < nrow; ++i) {
      const float4 v = *(const float4*)(p + (size_t)i * kC);
      acc.x += v.x; acc.y += v.y; acc.z += v.z; acc.w += v.w;
    }
    __shared__ float4 sred[160];
    if (h == 1) sred[c4] = acc;
    __syncthreads();
    if (h == 0) {
      const float4 o = sred[c4];
      acc.x += o.x; acc.y += o.y; acc.z += o.z; acc.w += o.w;
      float* dst = &s_l[b * kC + c4 * 4];
      atomicAdd(dst + 0, acc.x);
      atomicAdd(dst + 1, acc.y);
      atomicAdd(dst + 2, acc.z);
      atomicAdd(dst + 3, acc.w);
    }
  } else {
    const int wv = (blockIdx.x - 1840) * 5 + (tid >> 6);  // 0..799 = 40 dt x 20 kc
    const int lane = tid & 63;
    const int kc = wv % kKC, dt = wv / kKC;
    const int fm = lane & 15, quad = lane >> 4;
    const float* p = Wk + (size_t)(dt * 16 + fm) * kC + kc * 32 + quad * 8;
    float4 a = *(const float4*)p;
    float4 c = *(const float4*)(p + 4);
    S8U h, l;
    bsplit(a.x, h.u[0], l.u[0]); bsplit(a.y, h.u[1], l.u[1]);
    bsplit(a.z, h.u[2], l.u[2]); bsplit(a.w, h.u[3], l.u[3]);
    bsplit(c.x, h.u[4], l.u[4]); bsplit(c.y, h.u[5], l.u[5]);
    bsplit(c.z, h.u[6], l.u[6]); bsplit(c.w, h.u[7], l.u[7]);
    const size_t off = ((size_t)kc * 40 + dt) * 512 + (size_t)lane * 8;
    *(short8*)(Wh + off) = h.v;
    *(short8*)(Wl + off) = l.v;
  }
}

// One wave per (b,d): m[b,d] = (Wq[d]·sum_g gf + Wk[d]·s_l[b]) / 14705
// gc[b,g,d] = Wq[d]·gf[b,g] - m[b,d]
__global__ void k_proj_mean(const float* __restrict__ Wq, const float* __restrict__ Wk,
                            const float* __restrict__ gf, const float* __restrict__ s_l,
                            float* __restrict__ m, float* __restrict__ gc) {
  const int wid = blockIdx.x * 4 + (threadIdx.x >> 6);
  const int lane = threadIdx.x & 63;
  const int b = wid / kC, d = wid % kC;
  float ak = 0.f, ag[kNG] = {0.f, 0.f, 0.f, 0.f, 0.f};
  for (int c = lane; c < kC; c += 64) {
    const float wq = Wq[d * kC + c];
    const float wk = Wk[d * kC + c];
    ak += wk * s_l[b * kC + c];
#pragma unroll
    for (int g = 0; g < kNG; ++g) ag[g] += wq * gf[(b * kNG + g) * kC + c];
  }
#pragma unroll
  for (int off = 32; off > 0; off >>= 1) {
    ak += __shfl_xor(ak, off);
#pragma unroll
    for (int g = 0; g < kNG; ++g) ag[g] += __shfl_xor(ag[g], off);
  }
  if (lane == 0) {
    float aq = 0.f;
#pragma unroll
    for (int g = 0; g < kNG; ++g) aq += ag[g];
    const float mv = (aq + ak) / (float)kNTot;
    m[b * kC + d] = mv;
#pragma unroll
    for (int g = 0; g < kNG; ++g) gc[(b * kNG + g) * kC + d] = ag[g] - mv;
  }
}

__global__ void k_norm_g(const float* __restrict__ gc, float* __restrict__ gn) {
  const int row = blockIdx.x;
  __shared__ float red[256];
  float a = 0.f;
  for (int d = threadIdx.x; d < kC; d += 256) {
    const float v = gc[row * kC + d];
    a += v * v;
  }
  red[threadIdx.x] = a;
  __syncthreads();
  for (int s = 128; s > 0; s >>= 1) {
    if (threadIdx.x < s) red[threadIdx.x] += red[threadIdx.x + s];
    __syncthreads();
  }
  const float rs = 1.0f / sqrtf(red[0] + kEps);
  for (int d = threadIdx.x; d < kC; d += 256) gn[row * kC + d] = gc[row * kC + d] * rs;
}

// ---------- the big fused kernel ----------
// Block = 128 tokens x ALL 640 d. 512 threads / 8 waves; wave wn = 128 tok x
// 80 d (mt=8 x nt=5, acc=160 regs). Key change vs r5: 2x MFMAs per B-fragment
// batch (120 per 10KB L2 fetch) -> B traffic 1.5GB total, first-use latency
// amortized 4x better. A staged ONCE per block as bf16 hi/lo (full short8
// 16B ds_writes, conflict-free contiguous-1024B wave pattern). Per-mt
// {2 ds_read_b128 -> 15 MFMA} keeps live regs ~230 (2 waves/SIMD).
// K-step 64 (10 barriers). Per-acc MFMA chain (kc asc; hh->lh->hl)
// identical to r1/r5 -> bit-identical output.
__global__ __launch_bounds__(512, 2) void k_big(
    const float* __restrict__ lf, const ushort* __restrict__ Wh,
    const ushort* __restrict__ Wl, const float* __restrict__ m,
    const float* __restrict__ gn, float* __restrict__ scores) {
  __shared__ ushort smem[32768];  // 64KB: buf p @ p*16384; H @ kcL*4096, L @ +8192
  float* red = (float*)smem;      // epilogue overlay [8 waves][128 rows][6] = 24KB

  const int tid = threadIdx.x;
  const int wn = tid >> 6, lane = tid & 63;
  const int fm = lane & 15, quad = lane >> 4;
  const int b = blockIdx.x & 7, tile = blockIdx.x >> 3;
  const int tok0 = tile * 128;

  // staging role: token row sr (0..127), k-octet sq (0..3) within each 32-k
  const int sr = tid >> 2, sq = tid & 3;
  int strow = tok0 + sr;
  if (strow >= kNTokL) strow = kNTokL - 1;  // clamp: pad rows reuse last row (never written)
  const float* xrow = lf + ((size_t)b * kNTokL + strow) * kC + sq * 8;
  // LDS offset (shorts) within a kc half: tile (sr>>4), lane' = sq*16 + (sr&15)
  const int aoff = ((sr >> 4) << 9) + ((sq * 16 + (sr & 15)) << 3);

  floatx4 acc[8][kNT];
#pragma unroll
  for (int i = 0; i < 8; ++i)
#pragma unroll
    for (int j = 0; j < kNT; ++j) acc[i][j] = (floatx4){0.f, 0.f, 0.f, 0.f};

  // stage one kc (two float4 = one k-octet of 8) as short8 H + short8 L
#define STAGEKC(F0, F1, BUFOFF)                                        \
  {                                                                    \
    S8U _h, _l;                                                        \
    bsplit((F0).x, _h.u[0], _l.u[0]); bsplit((F0).y, _h.u[1], _l.u[1]);\
    bsplit((F0).z, _h.u[2], _l.u[2]); bsplit((F0).w, _h.u[3], _l.u[3]);\
    bsplit((F1).x, _h.u[4], _l.u[4]); bsplit((F1).y, _h.u[5], _l.u[5]);\
    bsplit((F1).z, _h.u[6], _l.u[6]); bsplit((F1).w, _h.u[7], _l.u[7]);\
    *(short8*)(smem + (BUFOFF) + aoff) = _h.v;                         \
    *(short8*)(smem + (BUFOFF) + 8192 + aoff) = _l.v;                  \
  }

  // one 32-k sub-chunk: B batch (10KB L2) then per-mt {2 ds_read, 15 MFMA}.
  // Per-acc order hh -> lh -> hl, kc ascending: identical to r1/r5.
#define DOSUB(BUF, KCL, KCI)                                                  \
  {                                                                           \
    const ushort* _bh = Wh + ((size_t)(KCI) * 40 + wn * 5) * 512 + (size_t)lane * 8; \
    const ushort* _bl = Wl + ((size_t)(KCI) * 40 + wn * 5) * 512 + (size_t)lane * 8; \
    short8 BH[kNT], BL[kNT];                                                  \
    _Pragma("unroll") for (int nt = 0; nt < kNT; ++nt) {                      \
      BH[nt] = *(const short8*)(_bh + nt * 512);                              \
      BL[nt] = *(const short8*)(_bl + nt * 512);                              \
    }                                                                         \
    _Pragma("unroll") for (int mt = 0; mt < 8; ++mt) {                        \
      const int _ba = (BUF) + (KCL) * 4096 + mt * 512 + lane * 8;             \
      const short8 ah = *(const short8*)(smem + _ba);                         \
      const short8 al = *(const short8*)(smem + _ba + 8192);                  \
      _Pragma("unroll") for (int nt = 0; nt < kNT; ++nt)                      \
          acc[mt][nt] = MFMA_BF16(ah, BH[nt], acc[mt][nt]);                   \
      _Pragma("unroll") for (int nt = 0; nt < kNT; ++nt)                      \
          acc[mt][nt] = MFMA_BF16(al, BH[nt], acc[mt][nt]);                   \
      _Pragma("unroll") for (int nt = 0; nt < kNT; ++nt)                      \
          acc[mt][nt] = MFMA_BF16(ah, BL[nt], acc[mt][nt]);                   \
    }                                                                         \
  }

  // prologue: stage K-step 0 into buf0; prefetch K-step 1 globals
  float4 x0 = *(const float4*)(xrow);
  float4 x1 = *(const float4*)(xrow + 4);
  float4 x2 = *(const float4*)(xrow + 32);
  float4 x3 = *(const float4*)(xrow + 36);
  STAGEKC(x0, x1, 0);
  STAGEKC(x2, x3, 4096);
  x0 = *(const float4*)(xrow + 64);
  x1 = *(const float4*)(xrow + 68);
  x2 = *(const float4*)(xrow + 96);
  x3 = *(const float4*)(xrow + 100);

  for (int t = 0; t < 10; ++t) {
    const int buf = (t & 1) * 16384;
    const int obuf = buf ^ 16384;
    // stage writes for t complete everywhere; all reads of obuf (step t-1) done
    bar_lds();
    if (t < 9) {
      STAGEKC(x0, x1, obuf);
      STAGEKC(x2, x3, obuf + 4096);
    }
    if (t < 8) {
      const float* xs = xrow + (t + 2) * 64;
      x0 = *(const float4*)(xs);
      x1 = *(const float4*)(xs + 4);
      x2 = *(const float4*)(xs + 32);
      x3 = *(const float4*)(xs + 36);
    }
    DOSUB(buf, 0, 2 * t);
    DOSUB(buf, 1, 2 * t + 1);
  }

  // ---- epilogue: center, reduce over d, combine 8 waves, write scores ----
  float mv[kNT], gvv[5][kNT];
#pragma unroll
  for (int nt = 0; nt < kNT; ++nt) {
    const int d = wn * 80 + nt * 16 + fm;
    mv[nt] = m[b * kC + d];
#pragma unroll
    for (int g = 0; g < 5; ++g) gvv[g][nt] = gn[(b * kNG + g) * kC + d];
  }

  bar_lds();  // all waves' K-loop ds_reads done before red[] overwrites bufs
#pragma unroll
  for (int mt = 0; mt < 8; ++mt)
#pragma unroll
    for (int reg = 0; reg < 4; ++reg) {
      float part[6] = {0.f, 0.f, 0.f, 0.f, 0.f, 0.f};
#pragma unroll
      for (int nt = 0; nt < kNT; ++nt) {
        const float yc = acc[mt][nt][reg] - mv[nt];
        part[0] += yc * yc;
#pragma unroll
        for (int g = 0; g < 5; ++g) part[1 + g] += yc * gvv[g][nt];
      }
#pragma unroll
      for (int off = 1; off < 16; off <<= 1)
#pragma unroll
        for (int v = 0; v < 6; ++v) part[v] += __shfl_xor(part[v], off);
      if (fm == 0) {
        const int row = mt * 16 + quad * 4 + reg;   // 0..127
#pragma unroll
        for (int v = 0; v < 6; ++v) red[((size_t)wn * 128 + row) * 6 + v] = part[v];
      }
    }
  bar_lds();
  if (tid < 128) {
    const int tok = tok0 + tid;
    if (tok < kNTokL) {
      float s[6] = {0.f, 0.f, 0.f, 0.f, 0.f, 0.f};
#pragma unroll
      for (int w = 0; w < 8; ++w)   // d-slices ascending (same order as r1/r5)
#pragma unroll
        for (int v = 0; v < 6; ++v) s[v] += red[((size_t)w * 128 + tid) * 6 + v];
      const float rs = (1.0f / sqrtf(s[0] + kEps)) * kInvAlpha;
      const size_t t = (size_t)b * kNTokL + tok;
#pragma unroll
      for (int g = 0; g < 5; ++g)
        scores[(size_t)g * (kB * kNTokL) + t] = s[1 + g] * rs;
    }
  }
#undef STAGEKC
#undef DOSUB
}

// softmax over f (196) per (b,l,g) row; one wave per row. scores pre-scaled.
__global__ void k_softmax(const float* __restrict__ scores, float* __restrict__ out) {
  const int wid = blockIdx.x * 4 + (threadIdx.x >> 6);
  const int lane = threadIdx.x & 63;
  const int b = wid / (kNL * kNG);
  const int rem = wid % (kNL * kNG);
  const int l = rem / kNG, g = rem % kNG;
  float sv[4];
  float mx = -1e30f;
#pragma unroll
  for (int u = 0; u < 4; ++u) {
    const int f = lane + 64 * u;
    if (f < kNF) {
      const size_t t = (size_t)b * kNTokL + (size_t)l * kNF + f;
      sv[u] = scores[(size_t)g * (kB * kNTokL) + t];
      mx = fmaxf(mx, sv[u]);
    } else {
      sv[u] = 0.f;
    }
  }
#pragma unroll
  for (int off = 32; off > 0; off >>= 1) mx = fmaxf(mx, __shfl_xor(mx, off));
  float se = 0.f;
#pragma unroll
  for (int u = 0; u < 4; ++u) {
    const int f = lane + 64 * u;
    const float e = (f < kNF) ? expf(sv[u] - mx) : 0.f;
    sv[u] = e;
    se += e;
  }
#pragma unroll
  for (int off = 32; off > 0; off >>= 1) se += __shfl_xor(se, off);
  const float inv = 1.0f / se;
#pragma unroll
  for (int u = 0; u < 4; ++u) {
    const int f = lane + 64 * u;
    if (f < kNF) out[((size_t)(b * kNL + l) * kNG + g) * kNF + f] = sv[u] * inv;
  }
}

// ===================== launcher =====================

extern "C" void kernel_launch(void* const* d_in, const int* in_sizes, int n_in,
                              void* d_out, int out_size, void* d_ws, size_t ws_size,
                              hipStream_t stream) {
  (void)in_sizes; (void)n_in; (void)out_size; (void)ws_size;
  const float* gf = (const float*)d_in[0];  // [8,5,640]
  const float* lf = (const float*)d_in[1];  // [8,75,196,640]
  const float* Wq = (const float*)d_in[2];  // [640,640]
  const float* Wk = (const float*)d_in[3];  // [640,640]
  float* ws = (float*)d_ws;
  float* out = (float*)d_out;

  // workspace (float offsets): total ~4.2 MB
  float* s_l    = ws;            // 5120
  float* m      = ws + 5120;     // 5120
  float* gc     = ws + 10240;    // 25600
  float* gn     = ws + 35840;    // 25600
  float* scores = ws + 61440;    // 5*117600 = 588000  (layout [g][t])
  ushort* Wh    = (ushort*)(ws + 649440);  // 409600 shorts
  ushort* Wl    = (ushort*)(ws + 854240);  // 409600 shorts

  hipMemsetAsync(s_l, 0, (size_t)5120 * 4, stream);

  k_sumcvt<<<2000, 320, 0, stream>>>(lf, s_l, Wk, Wh, Wl);
  k_proj_mean<<<(kB * kC) / 4, 256, 0, stream>>>(Wq, Wk, gf, s_l, m, gc);
  k_norm_g<<<kB * kNG, 256, 0, stream>>>(gc, gn);
  k_big<<<kTiles * kB, 512, 0, stream>>>(lf, Wh, Wl, m, gn, scores);
  k_softmax<<<750, 256, 0, stream>>>(scores, out);
}